// Round 5
// baseline (772.687 us; speedup 1.0000x reference)
//
#include <hip/hip_runtime.h>

// Problem constants (match reference setup_inputs / module constants)
#define EPS_F      1e-4f
#define GRID_RES_F 0.01f
#define ATOL_F     0.01f
#define RTOL_F     1e-5f

static constexpr int V = 1200;
static constexpr int E = 4800;
static constexpr int S = V + E;      // 6000 filtration points
static constexpr int P = 2500;
static constexpr int R = 3;

// Native vector type for nontemporal stores (HIP float4 is a class type,
// which __builtin_nontemporal_store rejects; this alias is layout-identical).
typedef float v4f __attribute__((ext_vector_type(4)));

// Output layout (flat fp32, return order):
//   bars0: [0, 7500)   bars1: [7500, 15000)
//   G0: (R,P,2S) at 15000   G1: follows   Gc0: (R,P,2)   Gc1: follows
static constexpr size_t G0_BASE  = 15000ull;
static constexpr size_t ROW_LEN  = 2ull * S;                 // 12000 floats per G row
static constexpr size_t G_ELEMS  = (size_t)R * P * ROW_LEN;  // 90,000,000
static constexpr size_t GC0_BASE = G0_BASE + 2 * G_ELEMS;    // 180,015,000

// ---------------------------------------------------------------------------
// Kernel 1: build filtration table. filt[j] = (fx, fy, tol_x, tol_y)
// ---------------------------------------------------------------------------
__global__ void build_filt_kernel(const float* __restrict__ f_v,
                                  const int*   __restrict__ edges,
                                  float4*      __restrict__ filt) {
    int j = blockIdx.x * blockDim.x + threadIdx.x;
    if (j >= S) return;
    float fx, fy;
    if (j < V) {
        fx = f_v[2 * j];
        fy = f_v[2 * j + 1];
    } else {
        int e = j - V;
        int a = edges[2 * e];
        int b = edges[2 * e + 1];
        fx = __fadd_rn(fmaxf(f_v[2 * a],     f_v[2 * b]),     EPS_F);
        fy = __fadd_rn(fmaxf(f_v[2 * a + 1], f_v[2 * b + 1]), EPS_F);
    }
    // tol = ATOL + RTOL*|f| with NumPy per-op rounding (no fma contraction).
    float tolx = __fadd_rn(ATOL_F, __fmul_rn(RTOL_F, fabsf(fx)));
    float toly = __fadd_rn(ATOL_F, __fmul_rn(RTOL_F, fabsf(fy)));
    filt[j] = make_float4(fx, fy, tolx, toly);
}

// ---------------------------------------------------------------------------
// min_k |l[k] - f| ; comparing vs tol is bit-exact-equivalent to
// any_k(|l[k]-f| <= tol) — min/cmp involve no rounding. Subs keep ref rounding.
// (Field-proven: absmax 0.0.)
// ---------------------------------------------------------------------------
__device__ __forceinline__ float mindist(const float* l, float f) {
    float a = fabsf(__fsub_rn(l[0], f));
    float b = fabsf(__fsub_rn(l[1], f));
    float c = fabsf(__fsub_rn(l[2], f));
    float d = fabsf(__fsub_rn(l[3], f));
    float e = fabsf(__fsub_rn(l[4], f));
    return fminf(fminf(fminf(a, b), fminf(c, d)), e);  // -> v_min3 pairs
}

__device__ __forceinline__ void cell(const float4& f, float psum,
                                     const float* lxs, const float* lys,
                                     float& vx, float& vy,
                                     int& aux, int& alx, int& auy, int& aly) {
    float fsum = __fadd_rn(f.x, f.y);
    bool ab = fsum > psum, be = fsum < psum;
    float sg = ab ? 1.0f : (be ? -1.0f : 0.0f);
    bool cx = (mindist(lxs, f.x) <= f.z) && (f.y <= lys[4]);
    bool cy = (mindist(lys, f.y) <= f.w) && (f.x <= lxs[4]);
    vx = cx ? sg : 0.0f;   // vx = ux - lx == condx ? (above - below) : 0
    vy = cy ? sg : 0.0f;
    aux |= (int)(cx && ab); alx |= (int)(cx && be);
    auy |= (int)(cy && ab); aly |= (int)(cy && be);
}

// ---------------------------------------------------------------------------
// Kernel 2: one block per (bar-set, r, p) — proven R1 structure, two changes
// forming one mechanism ("stream dense wave-spans to HBM, bypass L2"):
//   1. Instruction-dense stores: lane i owns cell pairs (jw+2i, jw+2i+1) and
//      (jw+128+2i, +1), so each global_store_dwordx4 is a contiguous 1KB
//      wave span (was: 16B-per-32B half-density pattern per instruction).
//   2. __builtin_nontemporal_store: G is write-once/never-read; bypassing L2
//      avoids dirty-line capacity evictions leaving in scrambled address
//      order (~2048 concurrent 48KB streams -> scattered 128B HBM writes),
//      the round-4 theory for the 267us-vs-114us write gap.
// Numerics bit-identical to the 726us kernel (same cell(); only store/load
// ordering permuted).
// ---------------------------------------------------------------------------
__global__ __launch_bounds__(256) void grad_kernel(
        const float4* __restrict__ filt,
        const float*  __restrict__ bars0,
        const float*  __restrict__ bars1,
        const float*  __restrict__ sample_pts,
        float*        __restrict__ d_out) {
    const int p = blockIdx.x;   // 0..P-1
    const int r = blockIdx.y;   // 0..R-1
    const int b = blockIdx.z;   // 0..1

    const float* bar = (b == 0) ? bars0 : bars1;
    const float px = sample_pts[2 * p];
    const float py = sample_pts[2 * p + 1];
    const float psum = __fadd_rn(px, py);
    const float s  = __fadd_rn(bar[p * R + r], GRID_RES_F);
    const float s2 = __fmul_rn(2.0f, s);   // exact (x2)

    float lxs[5], lys[5];
    lxs[0] = __fadd_rn(-s2, px); lxs[1] = __fadd_rn(-s, px); lxs[2] = px;
    lxs[3] = __fadd_rn( s, px);  lxs[4] = __fadd_rn(s2, px);
    lys[0] = __fadd_rn(-s2, py); lys[1] = __fadd_rn(-s, py); lys[2] = py;
    lys[3] = __fadd_rn( s, py);  lys[4] = __fadd_rn(s2, py);

    float* Grow = d_out + G0_BASE + (size_t)b * G_ELEMS
                        + ((size_t)(r * P + p)) * ROW_LEN;

    __shared__ int shw[4][4];   // [wave][flag]: ux, lx, uy, ly
    const int lane = threadIdx.x & 63;
    const int wv   = threadIdx.x >> 6;

    int aux = 0, alx = 0, auy = 0, aly = 0;

    // Wave w covers cells [jw, jw+256) per iter; lane i owns pairs at
    // jw+2i and jw+128+2i. Stores are lane-contiguous (16B * 64 = 1KB dense).
    int c0 = wv * 256 + 2 * lane;   // even
    int c1 = c0 + 128;
    float4 a0 = {}, a1 = {}, a2 = {}, a3 = {};
    if (c0 < S) { a0 = filt[c0]; a1 = filt[c0 + 1]; }
    if (c1 < S) { a2 = filt[c1]; a3 = filt[c1 + 1]; }
    while (c0 < S) {
        const int c0n = c0 + 1024, c1n = c1 + 1024;
        float4 b0 = {}, b1 = {}, b2 = {}, b3 = {};
        if (c0n < S) { b0 = filt[c0n]; b1 = filt[c0n + 1]; }
        if (c1n < S) { b2 = filt[c1n]; b3 = filt[c1n + 1]; }

        {   // cells c0, c0+1  (c0 < S, and S even => c0+1 < S)
            float ox, oy, oz, ow;
            cell(a0, psum, lxs, lys, ox, oy, aux, alx, auy, aly);
            cell(a1, psum, lxs, lys, oz, ow, aux, alx, auy, aly);
            v4f o; o.x = ox; o.y = oy; o.z = oz; o.w = ow;
            __builtin_nontemporal_store(o,
                reinterpret_cast<v4f*>(Grow + 2 * (size_t)c0));
        }
        if (c1 < S) {   // cells c1, c1+1
            float ox, oy, oz, ow;
            cell(a2, psum, lxs, lys, ox, oy, aux, alx, auy, aly);
            cell(a3, psum, lxs, lys, oz, ow, aux, alx, auy, aly);
            v4f o; o.x = ox; o.y = oy; o.z = oz; o.w = ow;
            __builtin_nontemporal_store(o,
                reinterpret_cast<v4f*>(Grow + 2 * (size_t)c1));
        }
        a0 = b0; a1 = b1; a2 = b2; a3 = b3;
        c0 = c0n; c1 = c1n;
    }

    // Block-wide any(): per-wave __any, lane 0 publishes, thread 0 combines.
    int f0 = __any(aux), f1 = __any(alx), f2 = __any(auy), f3 = __any(aly);
    if (lane == 0) {
        shw[wv][0] = f0; shw[wv][1] = f1; shw[wv][2] = f2; shw[wv][3] = f3;
    }
    __syncthreads();
    if (threadIdx.x == 0) {
        int ux = shw[0][0] | shw[1][0] | shw[2][0] | shw[3][0];
        int lx = shw[0][1] | shw[1][1] | shw[2][1] | shw[3][1];
        int uy = shw[0][2] | shw[1][2] | shw[2][2] | shw[3][2];
        int ly = shw[0][3] | shw[1][3] | shw[2][3] | shw[3][3];
        float cx = ux ? -1.0f : (lx ? 1.0f : 0.0f);
        float cy = uy ? -1.0f : (ly ? 1.0f : 0.0f);
        size_t gc = GC0_BASE + (size_t)b * ((size_t)R * P * 2)
                             + ((size_t)(r * P + p)) * 2;
        d_out[gc]     = cx;
        d_out[gc + 1] = cy;
    }
}

// ---------------------------------------------------------------------------
extern "C" void kernel_launch(void* const* d_in, const int* in_sizes, int n_in,
                              void* d_out, int out_size, void* d_ws, size_t ws_size,
                              hipStream_t stream) {
    const float* f_v        = (const float*)d_in[0];
    const int*   edges      = (const int*)d_in[1];
    const float* bars0      = (const float*)d_in[2];
    const float* bars1      = (const float*)d_in[3];
    const float* sample_pts = (const float*)d_in[4];
    float* out = (float*)d_out;

    float4* filt = (float4*)d_ws;   // S * 16 B = 96 KB scratch

    // bars0 / bars1 pass through to output.
    (void)hipMemcpyAsync(out,         bars0, (size_t)P * R * sizeof(float),
                         hipMemcpyDeviceToDevice, stream);
    (void)hipMemcpyAsync(out + P * R, bars1, (size_t)P * R * sizeof(float),
                         hipMemcpyDeviceToDevice, stream);

    build_filt_kernel<<<(S + 255) / 256, 256, 0, stream>>>(f_v, edges, filt);

    grad_kernel<<<dim3(P, R, 2), 256, 0, stream>>>(filt, bars0, bars1,
                                                   sample_pts, out);
}

// Round 6
// 721.480 us; speedup vs baseline: 1.0710x; 1.0710x over previous
//
#include <hip/hip_runtime.h>

// Problem constants (match reference setup_inputs / module constants)
#define EPS_F      1e-4f
#define GRID_RES_F 0.01f
#define ATOL_F     0.01f
#define RTOL_F     1e-5f

static constexpr int V = 1200;
static constexpr int E = 4800;
static constexpr int S = V + E;      // 6000 filtration points
static constexpr int P = 2500;
static constexpr int R = 3;

static constexpr int NROWS = 2 * R * P;          // 15000 G rows, address-ordered
static constexpr int NXCD  = 8;
static constexpr int ROWS_PER_XCD = NROWS / NXCD; // 1875 exactly

// Output layout (flat fp32, return order):
//   bars0: [0, 7500)   bars1: [7500, 15000)
//   G0: (R,P,2S) at 15000   G1: follows   Gc0: (R,P,2)   Gc1: follows
static constexpr size_t G0_BASE  = 15000ull;
static constexpr size_t ROW_LEN  = 2ull * S;                 // 12000 floats per G row
static constexpr size_t G_ELEMS  = (size_t)R * P * ROW_LEN;  // 90,000,000
static constexpr size_t GC0_BASE = G0_BASE + 2 * G_ELEMS;    // 180,015,000

// ---------------------------------------------------------------------------
// Kernel 1: build filtration table. filt[j] = (fx, fy, tol_x, tol_y)
// ---------------------------------------------------------------------------
__global__ void build_filt_kernel(const float* __restrict__ f_v,
                                  const int*   __restrict__ edges,
                                  float4*      __restrict__ filt) {
    int j = blockIdx.x * blockDim.x + threadIdx.x;
    if (j >= S) return;
    float fx, fy;
    if (j < V) {
        fx = f_v[2 * j];
        fy = f_v[2 * j + 1];
    } else {
        int e = j - V;
        int a = edges[2 * e];
        int b = edges[2 * e + 1];
        fx = __fadd_rn(fmaxf(f_v[2 * a],     f_v[2 * b]),     EPS_F);
        fy = __fadd_rn(fmaxf(f_v[2 * a + 1], f_v[2 * b + 1]), EPS_F);
    }
    // tol = ATOL + RTOL*|f| with NumPy per-op rounding (no fma contraction).
    float tolx = __fadd_rn(ATOL_F, __fmul_rn(RTOL_F, fabsf(fx)));
    float toly = __fadd_rn(ATOL_F, __fmul_rn(RTOL_F, fabsf(fy)));
    filt[j] = make_float4(fx, fy, tolx, toly);
}

// ---------------------------------------------------------------------------
// min_k |l[k] - f| ; comparing vs tol is bit-exact-equivalent to
// any_k(|l[k]-f| <= tol) — min/cmp involve no rounding. Subs keep ref rounding.
// (Field-proven: absmax 0.0.)
// ---------------------------------------------------------------------------
__device__ __forceinline__ float mindist(const float* l, float f) {
    float a = fabsf(__fsub_rn(l[0], f));
    float b = fabsf(__fsub_rn(l[1], f));
    float c = fabsf(__fsub_rn(l[2], f));
    float d = fabsf(__fsub_rn(l[3], f));
    float e = fabsf(__fsub_rn(l[4], f));
    return fminf(fminf(fminf(a, b), fminf(c, d)), e);  // -> v_min3 pairs
}

__device__ __forceinline__ void cell(const float4& f, float psum,
                                     const float* lxs, const float* lys,
                                     float& vx, float& vy,
                                     int& aux, int& alx, int& auy, int& aly) {
    float fsum = __fadd_rn(f.x, f.y);
    bool ab = fsum > psum, be = fsum < psum;
    float sg = ab ? 1.0f : (be ? -1.0f : 0.0f);
    bool cx = (mindist(lxs, f.x) <= f.z) && (f.y <= lys[4]);
    bool cy = (mindist(lys, f.y) <= f.w) && (f.x <= lxs[4]);
    vx = cx ? sg : 0.0f;   // vx = ux - lx == condx ? (above - below) : 0
    vy = cy ? sg : 0.0f;
    aux |= (int)(cx && ab); alx |= (int)(cx && be);
    auy |= (int)(cy && ab); aly |= (int)(cy && be);
}

// ---------------------------------------------------------------------------
// Kernel 2: bit-identical inner loop / stores to the 726us baseline. ONE
// change: XCD-contiguous row remap. Default dispatch round-robins
// consecutive blocks (adjacent G rows) across the 8 XCD L2s, so each XCD's
// dirty-eviction stream has 8x gaps and a ~100MB resident window. Remap
// rid = (i%8)*1875 + i/8 gives XCD k the contiguous rows
// [k*1875, (k+1)*1875) (90MB region), and co-resident blocks on one XCD
// (stride-8 dispatch => consecutive i/8) write CONSECUTIVE rows — a dense
// ~12MB moving window per XCD, matching the 6.3TB/s fill's access shape.
// ---------------------------------------------------------------------------
__global__ __launch_bounds__(256) void grad_kernel(
        const float4* __restrict__ filt,
        const float*  __restrict__ bars0,
        const float*  __restrict__ bars1,
        const float*  __restrict__ sample_pts,
        float*        __restrict__ d_out) {
    // XCD-contiguous bijective remap (15000 = 8 * 1875 exactly).
    const int i     = blockIdx.x;
    const int rid   = (i & (NXCD - 1)) * ROWS_PER_XCD + (i >> 3);
    // Address-ordered row id -> (b, r, p):  rid = b*(R*P) + r*P + p
    const int b   = rid / (R * P);
    const int rem = rid - b * (R * P);
    const int r   = rem / P;
    const int p   = rem - r * P;

    const float* bar = (b == 0) ? bars0 : bars1;
    const float px = sample_pts[2 * p];
    const float py = sample_pts[2 * p + 1];
    const float psum = __fadd_rn(px, py);
    const float s  = __fadd_rn(bar[p * R + r], GRID_RES_F);
    const float s2 = __fmul_rn(2.0f, s);   // exact (x2)

    float lxs[5], lys[5];
    lxs[0] = __fadd_rn(-s2, px); lxs[1] = __fadd_rn(-s, px); lxs[2] = px;
    lxs[3] = __fadd_rn( s, px);  lxs[4] = __fadd_rn(s2, px);
    lys[0] = __fadd_rn(-s2, py); lys[1] = __fadd_rn(-s, py); lys[2] = py;
    lys[3] = __fadd_rn( s, py);  lys[4] = __fadd_rn(s2, py);

    float* Grow = d_out + G0_BASE + (size_t)rid * ROW_LEN;

    __shared__ int sh_flags[4];
    if (threadIdx.x < 4) sh_flags[threadIdx.x] = 0;
    __syncthreads();

    int aux = 0, alx = 0, auy = 0, aly = 0;

    // 4 cells per thread per iteration; stride 1024 cells per block sweep.
    int j = threadIdx.x * 4;
    float4 a0, a1, a2, a3;
    if (j < S) { a0 = filt[j]; a1 = filt[j+1]; a2 = filt[j+2]; a3 = filt[j+3]; }
    while (j < S) {
        const int jn = j + 1024;
        float4 b0, b1, b2, b3;
        if (jn < S) {  // prefetch next iteration's cells before compute/store
            b0 = filt[jn]; b1 = filt[jn+1]; b2 = filt[jn+2]; b3 = filt[jn+3];
        }
        float4 o0, o1;
        cell(a0, psum, lxs, lys, o0.x, o0.y, aux, alx, auy, aly);
        cell(a1, psum, lxs, lys, o0.z, o0.w, aux, alx, auy, aly);
        cell(a2, psum, lxs, lys, o1.x, o1.y, aux, alx, auy, aly);
        cell(a3, psum, lxs, lys, o1.z, o1.w, aux, alx, auy, aly);
        float4* dst = reinterpret_cast<float4*>(Grow + 2 * j);
        dst[0] = o0;
        dst[1] = o1;
        a0 = b0; a1 = b1; a2 = b2; a3 = b3;
        j = jn;
    }

    // Row-wide any() flags: benign-race shared writes (all writers store 1).
    if (aux) sh_flags[0] = 1;
    if (alx) sh_flags[1] = 1;
    if (auy) sh_flags[2] = 1;
    if (aly) sh_flags[3] = 1;
    __syncthreads();

    if (threadIdx.x == 0) {
        float cx = sh_flags[0] ? -1.0f : (sh_flags[1] ? 1.0f : 0.0f);
        float cy = sh_flags[2] ? -1.0f : (sh_flags[3] ? 1.0f : 0.0f);
        size_t gc = GC0_BASE + (size_t)b * ((size_t)R * P * 2)
                             + ((size_t)(r * P + p)) * 2;
        d_out[gc]     = cx;
        d_out[gc + 1] = cy;
    }
}

// ---------------------------------------------------------------------------
extern "C" void kernel_launch(void* const* d_in, const int* in_sizes, int n_in,
                              void* d_out, int out_size, void* d_ws, size_t ws_size,
                              hipStream_t stream) {
    const float* f_v        = (const float*)d_in[0];
    const int*   edges      = (const int*)d_in[1];
    const float* bars0      = (const float*)d_in[2];
    const float* bars1      = (const float*)d_in[3];
    const float* sample_pts = (const float*)d_in[4];
    float* out = (float*)d_out;

    float4* filt = (float4*)d_ws;   // S * 16 B = 96 KB scratch

    // bars0 / bars1 pass through to output.
    (void)hipMemcpyAsync(out,         bars0, (size_t)P * R * sizeof(float),
                         hipMemcpyDeviceToDevice, stream);
    (void)hipMemcpyAsync(out + P * R, bars1, (size_t)P * R * sizeof(float),
                         hipMemcpyDeviceToDevice, stream);

    build_filt_kernel<<<(S + 255) / 256, 256, 0, stream>>>(f_v, edges, filt);

    grad_kernel<<<dim3(NROWS), 256, 0, stream>>>(filt, bars0, bars1,
                                                 sample_pts, out);
}